// Round 5
// baseline (2243.250 us; speedup 1.0000x reference)
//
#include <hip/hip_runtime.h>

// Problem constants (from reference)
#define NN 100000      // nodes
#define NE 1600000     // edges
#define NBATCH 100     // graphs
constexpr float EPS = 1e-5f;

__device__ __forceinline__ float lrelu(float x) { return x > 0.f ? x : 0.01f * x; }

// ---------------- CSR build ----------------

__global__ void k_hist(const int* __restrict__ dst, int* __restrict__ deg) {
    for (int e = blockIdx.x * blockDim.x + threadIdx.x; e < NE; e += gridDim.x * blockDim.x)
        atomicAdd(&deg[dst[e]], 1);
}

__global__ __launch_bounds__(1024) void k_scan(const int* __restrict__ deg,
                                               int* __restrict__ rowstart,
                                               int* __restrict__ cursor) {
    __shared__ int part[1024];
    const int t = threadIdx.x;
    const int chunk = (NN + 1023) / 1024;
    const int beg = t * chunk;
    const int end = (beg + chunk < NN) ? beg + chunk : NN;
    int s = 0;
    for (int i = beg; i < end; ++i) s += deg[i];
    part[t] = s;
    __syncthreads();
    for (int off = 1; off < 1024; off <<= 1) {
        int other = (t >= off) ? part[t - off] : 0;
        __syncthreads();
        part[t] += other;
        __syncthreads();
    }
    int run = part[t] - s;
    for (int i = beg; i < end; ++i) {
        rowstart[i] = run;
        cursor[i] = run;
        run += deg[i];
    }
    if (t == 0) rowstart[NN] = NE;
}

__global__ void k_fill(const int* __restrict__ dst, int* __restrict__ cursor,
                       int* __restrict__ csr_e) {
    for (int e = blockIdx.x * blockDim.x + threadIdx.x; e < NE; e += gridDim.x * blockDim.x) {
        int pos = atomicAdd(&cursor[dst[e]], 1);
        csr_e[pos] = e;
    }
}

// ---------------- batch boundaries (batch is sorted) ----------------

__global__ void k_bounds(const int* __restrict__ batch, int* __restrict__ bstart) {
    int b = blockIdx.x * blockDim.x + threadIdx.x;
    if (b > NBATCH) return;
    int lo = 0, hi = NN;
    while (lo < hi) {
        int mid = (lo + hi) >> 1;
        if (batch[mid] < b) lo = mid + 1; else hi = mid;
    }
    bstart[b] = lo;
}

// ---------------- kernels ----------------

__global__ void k_gather(const int* __restrict__ xi, const float* __restrict__ emb,
                         float* __restrict__ x0) {
    int total = NN * 16;
    for (int idx = blockIdx.x * blockDim.x + threadIdx.x; idx < total; idx += gridDim.x * blockDim.x) {
        int n = idx >> 4, d = idx & 15;
        x0[idx] = emb[(xi[n] << 4) + d];
    }
}

// agg[n,:] = sum_{e: dst[e]==n} x[src[e],:] * ew[e]   (CSR gather, no atomics)
template <int D>
__global__ void k_aggregate(const float* __restrict__ x, const int* __restrict__ csr_e,
                            const int* __restrict__ rowstart, const int* __restrict__ src,
                            const float* __restrict__ ew, float* __restrict__ agg) {
    constexpr int LPN = D / 4;
    constexpr int NPB = 256 / LPN;
    const int lane = threadIdx.x % LPN;
    const int nsub = threadIdx.x / LPN;
    const int n = blockIdx.x * NPB + nsub;
    if (n >= NN) return;
    const int beg = rowstart[n], end = rowstart[n + 1];
    float4 acc = {0.f, 0.f, 0.f, 0.f};
    for (int i = beg; i < end; ++i) {
        const int e = csr_e[i];
        const int s = src[e];
        const float w = ew[e];
        const float4 v = *(const float4*)&x[(size_t)s * D + lane * 4];
        acc.x += v.x * w; acc.y += v.y * w; acc.z += v.z * w; acc.w += v.w * w;
    }
    *(float4*)&agg[(size_t)n * D + lane * 4] = acc;
}

// out[N,DOUT] = agg @ wrel + xin @ wroot + brel
// 64-row tile per block, FULL DOUT width (NSUB=DOUT/64 sub-tiles in registers).
// A staged once per k-step -> A read exactly once from HBM.
template <int DIN, int DOUT>
__global__ __launch_bounds__(256) void k_conv_gemm(
        const float* __restrict__ agg, const float* __restrict__ xin,
        const float* __restrict__ wrel, const float* __restrict__ brel,
        const float* __restrict__ wroot, float* __restrict__ out) {
    constexpr int BK = 16;
    constexpr int AS = 68;
    constexpr int NSUB = DOUT / 64;
    __shared__ float sAa[BK][AS];
    __shared__ float sAx[BK][AS];
    __shared__ float sWr[BK][DOUT];
    __shared__ float sWo[BK][DOUT];

    const int tid = threadIdx.x;
    const int n0 = blockIdx.x * 64;
    const int tr = tid >> 4;               // 0..15 -> rows tr*4..tr*4+3
    const int tc = tid & 15;               // 0..15 -> col group

    const int ar = tid >> 2;               // 0..63
    const int ac = (tid & 3) * 4;          // {0,4,8,12}
    const int wkr = tid >> 4;              // 0..15
    const int wc = (tid & 15) * 4;         // {0..60}
    int an = n0 + ar; if (an >= NN) an = NN - 1;

    float acc[4][4 * NSUB] = {};

    for (int kk = 0; kk < DIN; kk += BK) {
        const float4 a4 = *(const float4*)&agg[(size_t)an * DIN + kk + ac];
        const float4 x4 = *(const float4*)&xin[(size_t)an * DIN + kk + ac];
        float4 wr4[NSUB], wo4[NSUB];
#pragma unroll
        for (int s = 0; s < NSUB; ++s) {
            wr4[s] = *(const float4*)&wrel[(size_t)(kk + wkr) * DOUT + s * 64 + wc];
            wo4[s] = *(const float4*)&wroot[(size_t)(kk + wkr) * DOUT + s * 64 + wc];
        }
        __syncthreads();
        sAa[ac + 0][ar] = a4.x; sAa[ac + 1][ar] = a4.y; sAa[ac + 2][ar] = a4.z; sAa[ac + 3][ar] = a4.w;
        sAx[ac + 0][ar] = x4.x; sAx[ac + 1][ar] = x4.y; sAx[ac + 2][ar] = x4.z; sAx[ac + 3][ar] = x4.w;
#pragma unroll
        for (int s = 0; s < NSUB; ++s) {
            *(float4*)&sWr[wkr][s * 64 + wc] = wr4[s];
            *(float4*)&sWo[wkr][s * 64 + wc] = wo4[s];
        }
        __syncthreads();
#pragma unroll
        for (int k = 0; k < BK; ++k) {
            const float4 aA = *(const float4*)&sAa[k][tr * 4];
            const float4 aX = *(const float4*)&sAx[k][tr * 4];
            const float a_[4] = {aA.x, aA.y, aA.z, aA.w};
            const float x_[4] = {aX.x, aX.y, aX.z, aX.w};
#pragma unroll
            for (int s = 0; s < NSUB; ++s) {
                const float4 br = *(const float4*)&sWr[k][s * 64 + tc * 4];
                const float4 bo = *(const float4*)&sWo[k][s * 64 + tc * 4];
                const float r_[4] = {br.x, br.y, br.z, br.w};
                const float o_[4] = {bo.x, bo.y, bo.z, bo.w};
#pragma unroll
                for (int i = 0; i < 4; ++i)
#pragma unroll
                    for (int j = 0; j < 4; ++j)
                        acc[i][s * 4 + j] += a_[i] * r_[j] + x_[i] * o_[j];
            }
        }
    }

#pragma unroll
    for (int s = 0; s < NSUB; ++s) {
        const float4 b4 = *(const float4*)&brel[s * 64 + tc * 4];
        const float bb[4] = {b4.x, b4.y, b4.z, b4.w};
#pragma unroll
        for (int i = 0; i < 4; ++i) {
            const int n = n0 + tr * 4 + i;
            if (n < NN) {
                float4 o;
                o.x = acc[i][s * 4 + 0] + bb[0];
                o.y = acc[i][s * 4 + 1] + bb[1];
                o.z = acc[i][s * 4 + 2] + bb[2];
                o.w = acc[i][s * 4 + 3] + bb[3];
                *(float4*)&out[(size_t)n * DOUT + s * 64 + tc * 4] = o;
            }
        }
    }
}

// graph-norm + lrelu, batch-contiguous, no atomics.
template <int D>
__global__ __launch_bounds__(256) void k_graphnorm(
        float* __restrict__ x, const int* __restrict__ bstart,
        const float* __restrict__ a, const float* __restrict__ g,
        const float* __restrict__ bb) {
    __shared__ float red[256];
    const int b = blockIdx.x;
    const int col = blockIdx.y * 64 + (threadIdx.x & 63);
    const int rg = threadIdx.x >> 6;
    const int beg = bstart[b], end = bstart[b + 1];
    const float cntf = fmaxf((float)(end - beg), 1.f);

    float s = 0.f;
    for (int r = beg + rg; r < end; r += 4) s += x[(size_t)r * D + col];
    red[threadIdx.x] = s;
    __syncthreads();
    if (rg == 0) {
        s += red[threadIdx.x + 64] + red[threadIdx.x + 128] + red[threadIdx.x + 192];
        red[threadIdx.x] = s / cntf;
    }
    __syncthreads();
    const float mean = red[threadIdx.x & 63];
    const float alpha = a[col];
    __syncthreads();

    float v = 0.f;
    for (int r = beg + rg; r < end; r += 4) {
        float xc = x[(size_t)r * D + col] - alpha * mean;
        v += xc * xc;
    }
    red[threadIdx.x] = v;
    __syncthreads();
    if (rg == 0) {
        v += red[threadIdx.x + 64] + red[threadIdx.x + 128] + red[threadIdx.x + 192];
        red[threadIdx.x] = 1.f / sqrtf(v / cntf + EPS);
    }
    __syncthreads();
    const float inv = red[threadIdx.x & 63];
    const float gg = g[col], bbv = bb[col];

    for (int r = beg + rg; r < end; r += 4) {
        float xc = x[(size_t)r * D + col] - alpha * mean;
        float y = gg * xc * inv + bbv;
        x[(size_t)r * D + col] = lrelu(y);
    }
}

// graph-feature mean into h0 (stride 272, cols 0..255)
__global__ __launch_bounds__(256) void k_gf2(const float* __restrict__ x3,
                                             const int* __restrict__ bstart,
                                             float* __restrict__ h0) {
    __shared__ float red[256];
    const int b = blockIdx.x;
    const int col = blockIdx.y * 64 + (threadIdx.x & 63);
    const int rg = threadIdx.x >> 6;
    const int beg = bstart[b], end = bstart[b + 1];
    const float cntf = fmaxf((float)(end - beg), 1.f);
    float s = 0.f;
    for (int r = beg + rg; r < end; r += 4) s += x3[(size_t)r * 256 + col];
    red[threadIdx.x] = s;
    __syncthreads();
    if (rg == 0) {
        s += red[threadIdx.x + 64] + red[threadIdx.x + 128] + red[threadIdx.x + 192];
        h0[b * 272 + col] = s / cntf;
    }
}

__global__ void k_demo(const float* __restrict__ dg, const float* __restrict__ w,
                       const float* __restrict__ b, float* __restrict__ h0) {
    int idx = blockIdx.x * blockDim.x + threadIdx.x;
    if (idx < NBATCH * 16) {
        int i = idx >> 4, j = idx & 15;
        float acc = b[j];
        for (int k = 0; k < 4; ++k) acc += dg[i * 4 + k] * w[k * 16 + j];
        h0[i * 272 + 256 + j] = acc;
    }
}

__global__ void k_linear(const float* __restrict__ in, const float* __restrict__ w,
                         const float* __restrict__ b, float* __restrict__ out,
                         int rows, int K, int D) {
    int total = rows * D;
    for (int idx = blockIdx.x * blockDim.x + threadIdx.x; idx < total; idx += gridDim.x * blockDim.x) {
        int i = idx / D, j = idx - i * D;
        float acc = b[j];
        for (int k = 0; k < K; ++k) acc += in[i * K + k] * w[k * D + j];
        out[idx] = acc;
    }
}

__global__ void k_bn_lrelu(float* __restrict__ h, const float* __restrict__ g,
                           const float* __restrict__ b, int rows, int C) {
    int j = threadIdx.x;
    if (j >= C) return;
    float s = 0.f;
    for (int i = 0; i < rows; ++i) s += h[i * C + j];
    float m = s / rows;
    float v = 0.f;
    for (int i = 0; i < rows; ++i) { float d = h[i * C + j] - m; v += d * d; }
    v /= rows;
    float inv = 1.f / sqrtf(v + EPS);
    float gg = g[j], bb = b[j];
    for (int i = 0; i < rows; ++i) {
        float y = gg * (h[i * C + j] - m) * inv + bb;
        h[i * C + j] = lrelu(y);
    }
}

// ---------------- launcher ----------------

extern "C" void kernel_launch(void* const* d_in, const int* in_sizes, int n_in,
                              void* d_out, int out_size, void* d_ws, size_t ws_size,
                              hipStream_t stream) {
    const int*   x_idx  = (const int*)d_in[0];
    const int*   ei     = (const int*)d_in[1];
    const float* eattr  = (const float*)d_in[2];
    const int*   batch  = (const int*)d_in[3];
    const float* demog  = (const float*)d_in[4];
    const float* emb    = (const float*)d_in[5];
    const float* wrel1  = (const float*)d_in[6];
    const float* brel1  = (const float*)d_in[7];
    const float* wroot1 = (const float*)d_in[8];
    const float* wrel2  = (const float*)d_in[9];
    const float* brel2  = (const float*)d_in[10];
    const float* wroot2 = (const float*)d_in[11];
    const float* wrel3  = (const float*)d_in[12];
    const float* brel3  = (const float*)d_in[13];
    const float* wroot3 = (const float*)d_in[14];
    const float* gn1g = (const float*)d_in[15];
    const float* gn1b = (const float*)d_in[16];
    const float* gn1a = (const float*)d_in[17];
    const float* gn2g = (const float*)d_in[18];
    const float* gn2b = (const float*)d_in[19];
    const float* gn2a = (const float*)d_in[20];
    const float* dw   = (const float*)d_in[21];
    const float* db   = (const float*)d_in[22];
    const float* l1w  = (const float*)d_in[23];
    const float* l1b  = (const float*)d_in[24];
    const float* bn1g = (const float*)d_in[25];
    const float* bn1b = (const float*)d_in[26];
    const float* l2w  = (const float*)d_in[27];
    const float* l2b  = (const float*)d_in[28];
    const float* bn2g = (const float*)d_in[29];
    const float* bn2b = (const float*)d_in[30];
    const float* l3w  = (const float*)d_in[31];
    const float* l3b  = (const float*)d_in[32];
    float* out = (float*)d_out;

    float* W    = (float*)d_ws;
    float* x2   = W;
    float* agg2 = W + 12800000;
    float* x3   = W + 25600000;
    float* x1   = W + 25600000;
    float* agg1 = W + 32000000;
    float* x0   = W + 38400000;
    float* agg0 = W + 40000000;
    int*   csr_e    = (int*)(W + 51200000);      // NE
    int*   rowstart = (int*)(W + 52800000);      // NN+1
    int*   cursor   = (int*)(W + 52920000);      // NN
    int*   deg      = (int*)(W + 53040000);      // NN
    int*   bstart   = (int*)(W + 53160000);      // NBATCH+1
    float* h0   = W + 53161000;                  // 100*272
    float* h1   = h0 + 27200;                    // 100*128
    float* h2   = h1 + 12800;                    // 100*64

    const int* src = ei;
    const int* dst = ei + NE;

    auto gsz = [](long long t) {
        long long b = (t + 255) / 256;
        return (int)(b > 524288 ? 524288 : b);
    };
    const int nrow_blk = (NN + 63) / 64;   // 1563

    // ---- CSR build (by dst) ----
    hipMemsetAsync(deg, 0, NN * sizeof(int), stream);
    k_hist<<<gsz(NE), 256, 0, stream>>>(dst, deg);
    k_scan<<<1, 1024, 0, stream>>>(deg, rowstart, cursor);
    k_fill<<<gsz(NE), 256, 0, stream>>>(dst, cursor, csr_e);

    // batch boundaries (batch sorted)
    k_bounds<<<1, 128, 0, stream>>>(batch, bstart);

    // x0 = emb[x_idx]
    k_gather<<<gsz((long long)NN * 16), 256, 0, stream>>>(x_idx, emb, x0);

    // conv1: 16 -> 64
    k_aggregate<16><<<(NN + 63) / 64, 256, 0, stream>>>(x0, csr_e, rowstart, src, eattr, agg0);
    k_conv_gemm<16, 64><<<nrow_blk, 256, 0, stream>>>(agg0, x0, wrel1, brel1, wroot1, x1);
    k_graphnorm<64><<<dim3(NBATCH, 1), 256, 0, stream>>>(x1, bstart, gn1a, gn1g, gn1b);

    // conv2: 64 -> 128
    k_aggregate<64><<<(NN + 15) / 16, 256, 0, stream>>>(x1, csr_e, rowstart, src, eattr, agg1);
    k_conv_gemm<64, 128><<<nrow_blk, 256, 0, stream>>>(agg1, x1, wrel2, brel2, wroot2, x2);
    k_graphnorm<128><<<dim3(NBATCH, 2), 256, 0, stream>>>(x2, bstart, gn2a, gn2g, gn2b);

    // conv3: 128 -> 256
    k_aggregate<128><<<(NN + 7) / 8, 256, 0, stream>>>(x2, csr_e, rowstart, src, eattr, agg2);
    k_conv_gemm<128, 256><<<nrow_blk, 256, 0, stream>>>(agg2, x2, wrel3, brel3, wroot3, x3);

    // head
    k_gf2<<<dim3(NBATCH, 4), 256, 0, stream>>>(x3, bstart, h0);
    k_demo<<<(NBATCH * 16 + 255) / 256, 256, 0, stream>>>(demog, dw, db, h0);

    k_linear<<<gsz(NBATCH * 128), 256, 0, stream>>>(h0, l1w, l1b, h1, NBATCH, 272, 128);
    k_bn_lrelu<<<1, 128, 0, stream>>>(h1, bn1g, bn1b, NBATCH, 128);
    k_linear<<<gsz(NBATCH * 64), 256, 0, stream>>>(h1, l2w, l2b, h2, NBATCH, 128, 64);
    k_bn_lrelu<<<1, 64, 0, stream>>>(h2, bn2g, bn2b, NBATCH, 64);
    k_linear<<<gsz(NBATCH * 3), 256, 0, stream>>>(h2, l3w, l3b, out, NBATCH, 64, 3);
}

// Round 6
// 1866.038 us; speedup vs baseline: 1.2021x; 1.2021x over previous
//
#include <hip/hip_runtime.h>

// Problem constants (from reference)
#define NN 100000      // nodes
#define NE 1600000     // edges
#define NBATCH 100     // graphs
constexpr float EPS = 1e-5f;

__device__ __forceinline__ float lrelu(float x) { return x > 0.f ? x : 0.01f * x; }

// ---------------- CSR build ----------------

__global__ void k_hist(const int* __restrict__ dst, int* __restrict__ deg) {
    for (int e = blockIdx.x * blockDim.x + threadIdx.x; e < NE; e += gridDim.x * blockDim.x)
        atomicAdd(&deg[dst[e]], 1);
}

__global__ __launch_bounds__(1024) void k_scan(const int* __restrict__ deg,
                                               int* __restrict__ rowstart,
                                               int* __restrict__ cursor) {
    __shared__ int part[1024];
    const int t = threadIdx.x;
    const int chunk = (NN + 1023) / 1024;
    const int beg = t * chunk;
    const int end = (beg + chunk < NN) ? beg + chunk : NN;
    int s = 0;
    for (int i = beg; i < end; ++i) s += deg[i];
    part[t] = s;
    __syncthreads();
    for (int off = 1; off < 1024; off <<= 1) {
        int other = (t >= off) ? part[t - off] : 0;
        __syncthreads();
        part[t] += other;
        __syncthreads();
    }
    int run = part[t] - s;
    for (int i = beg; i < end; ++i) {
        rowstart[i] = run;
        cursor[i] = run;
        run += deg[i];
    }
    if (t == 0) rowstart[NN] = NE;
}

__global__ void k_fill(const int* __restrict__ dst, int* __restrict__ cursor,
                       int* __restrict__ csr_e) {
    for (int e = blockIdx.x * blockDim.x + threadIdx.x; e < NE; e += gridDim.x * blockDim.x) {
        int pos = atomicAdd(&cursor[dst[e]], 1);
        csr_e[pos] = e;
    }
}

// ---------------- batch boundaries (batch is sorted) ----------------

__global__ void k_bounds(const int* __restrict__ batch, int* __restrict__ bstart) {
    int b = blockIdx.x * blockDim.x + threadIdx.x;
    if (b > NBATCH) return;
    int lo = 0, hi = NN;
    while (lo < hi) {
        int mid = (lo + hi) >> 1;
        if (batch[mid] < b) lo = mid + 1; else hi = mid;
    }
    bstart[b] = lo;
}

// ---------------- kernels ----------------

__global__ void k_gather(const int* __restrict__ xi, const float* __restrict__ emb,
                         float* __restrict__ x0) {
    int total = NN * 16;
    for (int idx = blockIdx.x * blockDim.x + threadIdx.x; idx < total; idx += gridDim.x * blockDim.x) {
        int n = idx >> 4, d = idx & 15;
        x0[idx] = emb[(xi[n] << 4) + d];
    }
}

// agg[n,:] = sum_{e: dst[e]==n} x[src[e],:] * ew[e]   (CSR gather, no atomics)
template <int D>
__global__ void k_aggregate(const float* __restrict__ x, const int* __restrict__ csr_e,
                            const int* __restrict__ rowstart, const int* __restrict__ src,
                            const float* __restrict__ ew, float* __restrict__ agg) {
    constexpr int LPN = D / 4;
    constexpr int NPB = 256 / LPN;
    const int lane = threadIdx.x % LPN;
    const int nsub = threadIdx.x / LPN;
    const int n = blockIdx.x * NPB + nsub;
    if (n >= NN) return;
    const int beg = rowstart[n], end = rowstart[n + 1];
    float4 acc = {0.f, 0.f, 0.f, 0.f};
    for (int i = beg; i < end; ++i) {
        const int e = csr_e[i];
        const int s = src[e];
        const float w = ew[e];
        const float4 v = *(const float4*)&x[(size_t)s * D + lane * 4];
        acc.x += v.x * w; acc.y += v.y * w; acc.z += v.z * w; acc.w += v.w * w;
    }
    *(float4*)&agg[(size_t)n * D + lane * 4] = acc;
}

// out[N,DOUT] = agg @ wrel + xin @ wroot + brel
// 64x64 tile, BK=16, 4x4 micro-tile (VGPR~112). L2 locality via dispatch order:
// blockIdx.x = column tile (fast-varying) so all col-tiles of a row slab are
// dispatched back-to-back and A's repeat reads hit L2 instead of HBM.
template <int DIN, int DOUT>
__global__ __launch_bounds__(256) void k_conv_gemm(
        const float* __restrict__ agg, const float* __restrict__ xin,
        const float* __restrict__ wrel, const float* __restrict__ brel,
        const float* __restrict__ wroot, float* __restrict__ out) {
    constexpr int BK = 16;
    constexpr int AS = 68;
    __shared__ float sAa[BK][AS];
    __shared__ float sAx[BK][AS];
    __shared__ float sWr[BK][64];
    __shared__ float sWo[BK][64];

    const int tid = threadIdx.x;
    const int c0 = blockIdx.x * 64;        // fast axis: column tile
    const int n0 = blockIdx.y * 64;        // slow axis: row tile
    const int tr = tid >> 4;
    const int tc = tid & 15;

    const int ar = tid >> 2;
    const int ac = (tid & 3) * 4;
    const int wkr = tid >> 4;
    const int wc = (tid & 15) * 4;
    int an = n0 + ar; if (an >= NN) an = NN - 1;

    float acc[4][4] = {};

    for (int kk = 0; kk < DIN; kk += BK) {
        const float4 a4 = *(const float4*)&agg[(size_t)an * DIN + kk + ac];
        const float4 x4 = *(const float4*)&xin[(size_t)an * DIN + kk + ac];
        const float4 wr4 = *(const float4*)&wrel[(size_t)(kk + wkr) * DOUT + c0 + wc];
        const float4 wo4 = *(const float4*)&wroot[(size_t)(kk + wkr) * DOUT + c0 + wc];
        __syncthreads();
        sAa[ac + 0][ar] = a4.x; sAa[ac + 1][ar] = a4.y; sAa[ac + 2][ar] = a4.z; sAa[ac + 3][ar] = a4.w;
        sAx[ac + 0][ar] = x4.x; sAx[ac + 1][ar] = x4.y; sAx[ac + 2][ar] = x4.z; sAx[ac + 3][ar] = x4.w;
        *(float4*)&sWr[wkr][wc] = wr4;
        *(float4*)&sWo[wkr][wc] = wo4;
        __syncthreads();
#pragma unroll
        for (int k = 0; k < BK; ++k) {
            const float4 aA = *(const float4*)&sAa[k][tr * 4];
            const float4 aX = *(const float4*)&sAx[k][tr * 4];
            const float4 br = *(const float4*)&sWr[k][tc * 4];
            const float4 bo = *(const float4*)&sWo[k][tc * 4];
            const float a_[4] = {aA.x, aA.y, aA.z, aA.w};
            const float x_[4] = {aX.x, aX.y, aX.z, aX.w};
            const float r_[4] = {br.x, br.y, br.z, br.w};
            const float o_[4] = {bo.x, bo.y, bo.z, bo.w};
#pragma unroll
            for (int i = 0; i < 4; ++i)
#pragma unroll
                for (int j = 0; j < 4; ++j)
                    acc[i][j] += a_[i] * r_[j] + x_[i] * o_[j];
        }
    }

    const float4 b4 = *(const float4*)&brel[c0 + tc * 4];
    const float bb[4] = {b4.x, b4.y, b4.z, b4.w};
#pragma unroll
    for (int i = 0; i < 4; ++i) {
        const int n = n0 + tr * 4 + i;
        if (n < NN) {
            float4 o;
            o.x = acc[i][0] + bb[0];
            o.y = acc[i][1] + bb[1];
            o.z = acc[i][2] + bb[2];
            o.w = acc[i][3] + bb[3];
            *(float4*)&out[(size_t)n * DOUT + c0 + tc * 4] = o;
        }
    }
}

// graph-norm + lrelu, batch-contiguous, no atomics.
template <int D>
__global__ __launch_bounds__(256) void k_graphnorm(
        float* __restrict__ x, const int* __restrict__ bstart,
        const float* __restrict__ a, const float* __restrict__ g,
        const float* __restrict__ bb) {
    __shared__ float red[256];
    const int b = blockIdx.x;
    const int col = blockIdx.y * 64 + (threadIdx.x & 63);
    const int rg = threadIdx.x >> 6;
    const int beg = bstart[b], end = bstart[b + 1];
    const float cntf = fmaxf((float)(end - beg), 1.f);

    float s = 0.f;
    for (int r = beg + rg; r < end; r += 4) s += x[(size_t)r * D + col];
    red[threadIdx.x] = s;
    __syncthreads();
    if (rg == 0) {
        s += red[threadIdx.x + 64] + red[threadIdx.x + 128] + red[threadIdx.x + 192];
        red[threadIdx.x] = s / cntf;
    }
    __syncthreads();
    const float mean = red[threadIdx.x & 63];
    const float alpha = a[col];
    __syncthreads();

    float v = 0.f;
    for (int r = beg + rg; r < end; r += 4) {
        float xc = x[(size_t)r * D + col] - alpha * mean;
        v += xc * xc;
    }
    red[threadIdx.x] = v;
    __syncthreads();
    if (rg == 0) {
        v += red[threadIdx.x + 64] + red[threadIdx.x + 128] + red[threadIdx.x + 192];
        red[threadIdx.x] = 1.f / sqrtf(v / cntf + EPS);
    }
    __syncthreads();
    const float inv = red[threadIdx.x & 63];
    const float gg = g[col], bbv = bb[col];

    for (int r = beg + rg; r < end; r += 4) {
        float xc = x[(size_t)r * D + col] - alpha * mean;
        float y = gg * xc * inv + bbv;
        x[(size_t)r * D + col] = lrelu(y);
    }
}

// graph-feature mean into h0 (stride 272, cols 0..255)
__global__ __launch_bounds__(256) void k_gf2(const float* __restrict__ x3,
                                             const int* __restrict__ bstart,
                                             float* __restrict__ h0) {
    __shared__ float red[256];
    const int b = blockIdx.x;
    const int col = blockIdx.y * 64 + (threadIdx.x & 63);
    const int rg = threadIdx.x >> 6;
    const int beg = bstart[b], end = bstart[b + 1];
    const float cntf = fmaxf((float)(end - beg), 1.f);
    float s = 0.f;
    for (int r = beg + rg; r < end; r += 4) s += x3[(size_t)r * 256 + col];
    red[threadIdx.x] = s;
    __syncthreads();
    if (rg == 0) {
        s += red[threadIdx.x + 64] + red[threadIdx.x + 128] + red[threadIdx.x + 192];
        h0[b * 272 + col] = s / cntf;
    }
}

__global__ void k_demo(const float* __restrict__ dg, const float* __restrict__ w,
                       const float* __restrict__ b, float* __restrict__ h0) {
    int idx = blockIdx.x * blockDim.x + threadIdx.x;
    if (idx < NBATCH * 16) {
        int i = idx >> 4, j = idx & 15;
        float acc = b[j];
        for (int k = 0; k < 4; ++k) acc += dg[i * 4 + k] * w[k * 16 + j];
        h0[i * 272 + 256 + j] = acc;
    }
}

__global__ void k_linear(const float* __restrict__ in, const float* __restrict__ w,
                         const float* __restrict__ b, float* __restrict__ out,
                         int rows, int K, int D) {
    int total = rows * D;
    for (int idx = blockIdx.x * blockDim.x + threadIdx.x; idx < total; idx += gridDim.x * blockDim.x) {
        int i = idx / D, j = idx - i * D;
        float acc = b[j];
        for (int k = 0; k < K; ++k) acc += in[i * K + k] * w[k * D + j];
        out[idx] = acc;
    }
}

__global__ void k_bn_lrelu(float* __restrict__ h, const float* __restrict__ g,
                           const float* __restrict__ b, int rows, int C) {
    int j = threadIdx.x;
    if (j >= C) return;
    float s = 0.f;
    for (int i = 0; i < rows; ++i) s += h[i * C + j];
    float m = s / rows;
    float v = 0.f;
    for (int i = 0; i < rows; ++i) { float d = h[i * C + j] - m; v += d * d; }
    v /= rows;
    float inv = 1.f / sqrtf(v + EPS);
    float gg = g[j], bb = b[j];
    for (int i = 0; i < rows; ++i) {
        float y = gg * (h[i * C + j] - m) * inv + bb;
        h[i * C + j] = lrelu(y);
    }
}

// ---------------- launcher ----------------

extern "C" void kernel_launch(void* const* d_in, const int* in_sizes, int n_in,
                              void* d_out, int out_size, void* d_ws, size_t ws_size,
                              hipStream_t stream) {
    const int*   x_idx  = (const int*)d_in[0];
    const int*   ei     = (const int*)d_in[1];
    const float* eattr  = (const float*)d_in[2];
    const int*   batch  = (const int*)d_in[3];
    const float* demog  = (const float*)d_in[4];
    const float* emb    = (const float*)d_in[5];
    const float* wrel1  = (const float*)d_in[6];
    const float* brel1  = (const float*)d_in[7];
    const float* wroot1 = (const float*)d_in[8];
    const float* wrel2  = (const float*)d_in[9];
    const float* brel2  = (const float*)d_in[10];
    const float* wroot2 = (const float*)d_in[11];
    const float* wrel3  = (const float*)d_in[12];
    const float* brel3  = (const float*)d_in[13];
    const float* wroot3 = (const float*)d_in[14];
    const float* gn1g = (const float*)d_in[15];
    const float* gn1b = (const float*)d_in[16];
    const float* gn1a = (const float*)d_in[17];
    const float* gn2g = (const float*)d_in[18];
    const float* gn2b = (const float*)d_in[19];
    const float* gn2a = (const float*)d_in[20];
    const float* dw   = (const float*)d_in[21];
    const float* db   = (const float*)d_in[22];
    const float* l1w  = (const float*)d_in[23];
    const float* l1b  = (const float*)d_in[24];
    const float* bn1g = (const float*)d_in[25];
    const float* bn1b = (const float*)d_in[26];
    const float* l2w  = (const float*)d_in[27];
    const float* l2b  = (const float*)d_in[28];
    const float* bn2g = (const float*)d_in[29];
    const float* bn2b = (const float*)d_in[30];
    const float* l3w  = (const float*)d_in[31];
    const float* l3b  = (const float*)d_in[32];
    float* out = (float*)d_out;

    float* W    = (float*)d_ws;
    float* x2   = W;
    float* agg2 = W + 12800000;
    float* x3   = W + 25600000;
    float* x1   = W + 25600000;
    float* agg1 = W + 32000000;
    float* x0   = W + 38400000;
    float* agg0 = W + 40000000;
    int*   csr_e    = (int*)(W + 51200000);      // NE
    int*   rowstart = (int*)(W + 52800000);      // NN+1
    int*   cursor   = (int*)(W + 52920000);      // NN
    int*   deg      = (int*)(W + 53040000);      // NN
    int*   bstart   = (int*)(W + 53160000);      // NBATCH+1
    float* h0   = W + 53161000;                  // 100*272
    float* h1   = h0 + 27200;                    // 100*128
    float* h2   = h1 + 12800;                    // 100*64

    const int* src = ei;
    const int* dst = ei + NE;

    auto gsz = [](long long t) {
        long long b = (t + 255) / 256;
        return (int)(b > 524288 ? 524288 : b);
    };
    const int nrow_blk = (NN + 63) / 64;   // 1563

    // ---- CSR build (by dst) ----
    hipMemsetAsync(deg, 0, NN * sizeof(int), stream);
    k_hist<<<gsz(NE), 256, 0, stream>>>(dst, deg);
    k_scan<<<1, 1024, 0, stream>>>(deg, rowstart, cursor);
    k_fill<<<gsz(NE), 256, 0, stream>>>(dst, cursor, csr_e);

    // batch boundaries (batch sorted)
    k_bounds<<<1, 128, 0, stream>>>(batch, bstart);

    // x0 = emb[x_idx]
    k_gather<<<gsz((long long)NN * 16), 256, 0, stream>>>(x_idx, emb, x0);

    // conv1: 16 -> 64
    k_aggregate<16><<<(NN + 63) / 64, 256, 0, stream>>>(x0, csr_e, rowstart, src, eattr, agg0);
    k_conv_gemm<16, 64><<<dim3(1, nrow_blk), 256, 0, stream>>>(agg0, x0, wrel1, brel1, wroot1, x1);
    k_graphnorm<64><<<dim3(NBATCH, 1), 256, 0, stream>>>(x1, bstart, gn1a, gn1g, gn1b);

    // conv2: 64 -> 128
    k_aggregate<64><<<(NN + 15) / 16, 256, 0, stream>>>(x1, csr_e, rowstart, src, eattr, agg1);
    k_conv_gemm<64, 128><<<dim3(2, nrow_blk), 256, 0, stream>>>(agg1, x1, wrel2, brel2, wroot2, x2);
    k_graphnorm<128><<<dim3(NBATCH, 2), 256, 0, stream>>>(x2, bstart, gn2a, gn2g, gn2b);

    // conv3: 128 -> 256
    k_aggregate<128><<<(NN + 7) / 8, 256, 0, stream>>>(x2, csr_e, rowstart, src, eattr, agg2);
    k_conv_gemm<128, 256><<<dim3(4, nrow_blk), 256, 0, stream>>>(agg2, x2, wrel3, brel3, wroot3, x3);

    // head
    k_gf2<<<dim3(NBATCH, 4), 256, 0, stream>>>(x3, bstart, h0);
    k_demo<<<(NBATCH * 16 + 255) / 256, 256, 0, stream>>>(demog, dw, db, h0);

    k_linear<<<gsz(NBATCH * 128), 256, 0, stream>>>(h0, l1w, l1b, h1, NBATCH, 272, 128);
    k_bn_lrelu<<<1, 128, 0, stream>>>(h1, bn1g, bn1b, NBATCH, 128);
    k_linear<<<gsz(NBATCH * 64), 256, 0, stream>>>(h1, l2w, l2b, h2, NBATCH, 128, 64);
    k_bn_lrelu<<<1, 64, 0, stream>>>(h2, bn2g, bn2b, NBATCH, 64);
    k_linear<<<gsz(NBATCH * 3), 256, 0, stream>>>(h2, l3w, l3b, out, NBATCH, 64, 3);
}